// Round 3
// baseline (63.479 us; speedup 1.0000x reference)
//
#include <hip/hip_runtime.h>
#include <hip/hip_bf16.h>

#define B_DIM 4
#define T_DIM 4096
#define D_DIM 2048
#define K_SEL 2048   // top_k = int(0.5 * 4096)

// Module-scope scratch (independent of ws_size; deterministic — fully
// rewritten every launch).
__device__ double g_logits[B_DIM * T_DIM];
__device__ double g_partials[2 * B_DIM];

// ---------------------------------------------------------------------------
// order-preserving map: double -> uint64 (larger key <=> larger double)
__device__ inline unsigned long long keymap(double d) {
    unsigned long long b = (unsigned long long)__double_as_longlong(d);
    return (b & 0x8000000000000000ULL) ? ~b : (b | 0x8000000000000000ULL);
}

// exclusive scan of one unsigned per thread across 256 threads (4 waves)
__device__ inline unsigned block_excl_scan_256(unsigned v, unsigned* wtot, int tid) {
    unsigned inc = v;
    #pragma unroll
    for (int off = 1; off < 64; off <<= 1) {
        unsigned n = __shfl_up(inc, off, 64);
        if ((tid & 63) >= off) inc += n;
    }
    __syncthreads();                       // protect wtot from previous use
    if ((tid & 63) == 63) wtot[tid >> 6] = inc;
    __syncthreads();
    unsigned base = 0;
    for (int w = 0; w < (tid >> 6); ++w) base += wtot[w];
    return base + inc - v;
}

// ---------------------------------------------------------------------------
// K1: logits[b,t] = dot(x[b,t,:], W) in fp64.  One wave per row.
__global__ __launch_bounds__(256) void router_matvec(
    const float* __restrict__ x, const float* __restrict__ W,
    float* __restrict__ raw_out)
{
    const int row  = blockIdx.x * 4 + (threadIdx.x >> 6);   // 16384 rows
    const int lane = threadIdx.x & 63;
    const float4* xr = (const float4*)(x + (size_t)row * D_DIM);
    const float4* wr = (const float4*)W;
    double acc = 0.0;
    #pragma unroll
    for (int j = 0; j < 8; ++j) {
        float4 a = xr[lane + j * 64];
        float4 w = wr[lane + j * 64];
        acc = fma((double)a.x, (double)w.x, acc);
        acc = fma((double)a.y, (double)w.y, acc);
        acc = fma((double)a.z, (double)w.z, acc);
        acc = fma((double)a.w, (double)w.w, acc);
    }
    #pragma unroll
    for (int off = 32; off; off >>= 1) acc += __shfl_down(acc, off, 64);
    if (lane == 0) {
        g_logits[row] = acc;
        raw_out[row]  = (float)acc;
    }
}

// ---------------------------------------------------------------------------
// K2: per batch row — radix-select kth largest, compact selected (ascending),
// write sel_tokens + gate_weights, accumulate BCE and logsumexp partials.
__global__ __launch_bounds__(256) void router_select(
    float* __restrict__ out_sel,
    float* __restrict__ out_gate)
{
    const int b   = blockIdx.x;
    const int tid = threadIdx.x;

    __shared__ double ld[T_DIM];           // 32 KiB
    __shared__ unsigned hist[256];
    __shared__ unsigned wtot[4];
    __shared__ double dtot[4];
    __shared__ unsigned long long s_prefix;
    __shared__ unsigned s_remaining;
    __shared__ double s_max;

    for (int t = tid; t < T_DIM; t += 256) ld[t] = g_logits[(size_t)b * T_DIM + t];
    if (tid == 0) { s_prefix = 0ULL; s_remaining = K_SEL; }
    __syncthreads();

    // ---- 64-bit MSB-first radix select of the K_SEL-th largest key ----
    for (int p = 7; p >= 0; --p) {
        hist[tid] = 0;
        __syncthreads();
        const unsigned long long prefix  = s_prefix;
        const unsigned long long hi_mask = (p == 7) ? 0ULL : (~0ULL << ((p + 1) * 8));
        const unsigned rem = s_remaining;
        for (int t = tid; t < T_DIM; t += 256) {
            unsigned long long key = keymap(ld[t]);
            if (((key ^ prefix) & hi_mask) == 0ULL)
                atomicAdd(&hist[(unsigned)((key >> (p * 8)) & 255ULL)], 1u);
        }
        __syncthreads();
        // suffix-sum across bins: thread tid owns bin (255 - tid)
        unsigned v = hist[255 - tid];
        unsigned inc = v;
        #pragma unroll
        for (int off = 1; off < 64; off <<= 1) {
            unsigned n = __shfl_up(inc, off, 64);
            if ((tid & 63) >= off) inc += n;
        }
        if ((tid & 63) == 63) wtot[tid >> 6] = inc;
        __syncthreads();
        unsigned base = 0;
        for (int w = 0; w < (tid >> 6); ++w) base += wtot[w];
        inc += base;                       // inclusive suffix sum for my bin
        const unsigned bin = 255 - tid;
        const unsigned cum_above = inc - v;
        if (cum_above < rem && inc >= rem) {   // exactly one thread matches
            s_prefix    = prefix | ((unsigned long long)bin << (p * 8));
            s_remaining = rem - cum_above;
        }
        __syncthreads();
    }

    const unsigned long long K = s_prefix;    // k-th largest key value
    const unsigned need_eq     = s_remaining; // how many ==K to take (lowest idx)

    // ---- per-thread strip of 16 consecutive tokens ----
    const int t0 = tid * 16;
    unsigned long long key[16];
    #pragma unroll
    for (int i = 0; i < 16; ++i) key[i] = keymap(ld[t0 + i]);

    unsigned eqc = 0;
    #pragma unroll
    for (int i = 0; i < 16; ++i) eqc += (key[i] == K) ? 1u : 0u;
    unsigned eq_rank = block_excl_scan_256(eqc, wtot, tid);

    unsigned selmask = 0, selc = 0;
    {
        unsigned r = eq_rank;
        #pragma unroll
        for (int i = 0; i < 16; ++i) {
            bool eq  = (key[i] == K);
            bool sel = (key[i] > K) || (eq && r < need_eq);
            r += eq ? 1u : 0u;
            if (sel) { selmask |= (1u << i); ++selc; }
        }
    }
    unsigned pos = block_excl_scan_256(selc, wtot, tid);

    #pragma unroll
    for (int i = 0; i < 16; ++i) {
        if (selmask & (1u << i)) {
            if (pos < K_SEL) {   // defensive: never corrupt neighboring regions
                const int t = t0 + i;
                const double l = ld[t];
                out_sel [(size_t)b * K_SEL + pos] = (float)t;
                out_gate[(size_t)b * K_SEL + pos] =
                    (float)(0.1 / (1.0 + exp(-l)));
            }
            ++pos;
        }
    }

    // ---- losses: row max, then BCE sum + sum(exp(l-m)) ----
    double mx = -1.0e300;
    #pragma unroll
    for (int i = 0; i < 16; ++i) mx = fmax(mx, ld[t0 + i]);
    #pragma unroll
    for (int off = 32; off; off >>= 1) mx = fmax(mx, __shfl_down(mx, off, 64));
    __syncthreads();
    if ((tid & 63) == 0) dtot[tid >> 6] = mx;
    __syncthreads();
    if (tid == 0) s_max = fmax(fmax(dtot[0], dtot[1]), fmax(dtot[2], dtot[3]));
    __syncthreads();
    const double m = s_max;

    double bce = 0.0, se = 0.0;
    #pragma unroll
    for (int i = 0; i < 16; ++i) {
        const double l   = ld[t0 + i];
        const double tgt = ((selmask >> i) & 1u) ? 1.0 : 0.0;
        bce += fmax(l, 0.0) - l * tgt + log1p(exp(-fabs(l)));
        se  += exp(l - m);
    }
    #pragma unroll
    for (int off = 32; off; off >>= 1) bce += __shfl_down(bce, off, 64);
    __syncthreads();
    if ((tid & 63) == 0) dtot[tid >> 6] = bce;
    __syncthreads();
    if (tid == 0) g_partials[b] = dtot[0] + dtot[1] + dtot[2] + dtot[3];
    __syncthreads();
    #pragma unroll
    for (int off = 32; off; off >>= 1) se += __shfl_down(se, off, 64);
    if ((tid & 63) == 0) dtot[tid >> 6] = se;
    __syncthreads();
    if (tid == 0)
        g_partials[4 + b] = m + log(dtot[0] + dtot[1] + dtot[2] + dtot[3]);
}

// ---------------------------------------------------------------------------
// K3: finalize scalar losses.
__global__ void router_finalize(float* __restrict__ out2)
{
    double bce = g_partials[0] + g_partials[1] + g_partials[2] + g_partials[3];
    double aux = 0.001 * bce / (double)(B_DIM * T_DIM);
    double zz  = 0.0;
    for (int b = 0; b < B_DIM; ++b) { double z = g_partials[4 + b]; zz += z * z; }
    double zl = 0.001 * zz / (double)B_DIM;
    out2[0] = (float)aux;
    out2[1] = (float)zl;
}

// ---------------------------------------------------------------------------
extern "C" void kernel_launch(void* const* d_in, const int* in_sizes, int n_in,
                              void* d_out, int out_size, void* d_ws, size_t ws_size,
                              hipStream_t stream) {
    const float* x = (const float*)d_in[0];   // (4, 4096, 2048) fp32
    const float* W = (const float*)d_in[1];   // (1, 2048) fp32
    float* out = (float*)d_out;               // float32 outputs (NOT bf16)

    // out layout (float elems): sel[8192] | gate[8192] | raw[16384] | aux | z
    router_matvec  <<<(B_DIM * T_DIM) / 4, 256, 0, stream>>>(x, W, out + 16384);
    router_select  <<<B_DIM, 256, 0, stream>>>(out, out + 8192);
    router_finalize<<<1, 1, 0, stream>>>(out + 32768);
}

// Round 4
// 45.453 us; speedup vs baseline: 1.3966x; 1.3966x over previous
//
#include <hip/hip_runtime.h>

#define B_DIM 4
#define T_DIM 4096
#define D_DIM 2048
#define K_SEL 2048   // top_k = int(0.5 * 4096)

// Module-scope scratch (deterministic: fully rewritten every launch).
__device__ double g_logits[B_DIM * T_DIM];
__device__ double g_partials[2 * B_DIM];
__device__ unsigned g_done_ctr;   // reset by K1 each launch

typedef float f4v __attribute__((ext_vector_type(4)));

// order-preserving map: double -> uint64 (larger key <=> larger double)
__device__ inline unsigned long long keymap(double d) {
    unsigned long long b = (unsigned long long)__double_as_longlong(d);
    return (b & 0x8000000000000000ULL) ? ~b : (b | 0x8000000000000000ULL);
}

// exclusive scan of one unsigned per thread across 256 threads (4 waves)
__device__ inline unsigned block_excl_scan_256(unsigned v, unsigned* wtot, int tid) {
    unsigned inc = v;
    #pragma unroll
    for (int off = 1; off < 64; off <<= 1) {
        unsigned n = __shfl_up(inc, off, 64);
        if ((tid & 63) >= off) inc += n;
    }
    __syncthreads();                       // protect wtot from previous use
    if ((tid & 63) == 63) wtot[tid >> 6] = inc;
    __syncthreads();
    unsigned base = 0;
    for (int w = 0; w < (tid >> 6); ++w) base += wtot[w];
    return base + inc - v;
}

// ---------------------------------------------------------------------------
// K1: logits[b,t] = dot(x[b,t,:], W) in fp64.  One wave per row.
__global__ __launch_bounds__(256) void router_matvec(
    const float* __restrict__ x, const float* __restrict__ W,
    float* __restrict__ raw_out)
{
    if (blockIdx.x == 0 && threadIdx.x == 0) g_done_ctr = 0;  // reset fuse ctr
    const int row  = blockIdx.x * 4 + (threadIdx.x >> 6);   // 16384 rows
    const int lane = threadIdx.x & 63;
    const f4v* xr = (const f4v*)(x + (size_t)row * D_DIM);
    const f4v* wr = (const f4v*)W;
    double a0 = 0.0, a1 = 0.0;
    #pragma unroll
    for (int j = 0; j < 8; ++j) {
        f4v a = __builtin_nontemporal_load(xr + lane + j * 64);  // streamed, no reuse
        f4v w = wr[lane + j * 64];                               // cached (8 KB)
        a0 = fma((double)a.x, (double)w.x, a0);
        a0 = fma((double)a.y, (double)w.y, a0);
        a1 = fma((double)a.z, (double)w.z, a1);
        a1 = fma((double)a.w, (double)w.w, a1);
    }
    double acc = a0 + a1;
    #pragma unroll
    for (int off = 32; off; off >>= 1) acc += __shfl_down(acc, off, 64);
    if (lane == 0) {
        g_logits[row] = acc;
        raw_out[row]  = (float)acc;
    }
}

// ---------------------------------------------------------------------------
// K2: per batch row — early-exit radix-select, compact (ascending index),
// losses, and fused finalize (last block).
__global__ __launch_bounds__(256) void router_select(
    float* __restrict__ out_sel,
    float* __restrict__ out_gate,
    float* __restrict__ out_loss)
{
    const int b    = blockIdx.x;
    const int tid  = threadIdx.x;
    const int lane = tid & 63;

    __shared__ double ld[T_DIM];           // 32 KiB staging (coalesced load)
    __shared__ unsigned hist[256];
    __shared__ unsigned wtot[4];
    __shared__ double dtot[4];
    __shared__ unsigned long long s_prefix;
    __shared__ unsigned s_remaining;
    __shared__ int s_done;
    __shared__ int s_last;
    __shared__ double s_max;

    for (int t = tid; t < T_DIM; t += 256) ld[t] = g_logits[(size_t)b * T_DIM + t];
    if (tid == 0) { s_prefix = 0ULL; s_remaining = K_SEL; s_done = 0; s_last = 0; }
    __syncthreads();

    // per-thread strip of 16 consecutive tokens, values+keys in registers
    const int t0 = tid * 16;
    double v[16]; unsigned long long key[16];
    #pragma unroll
    for (int i = 0; i < 16; ++i) { v[i] = ld[t0 + i]; key[i] = keymap(v[i]); }

    // ---- MSB-first radix select with early exit ----
    for (int p = 7; p >= 0; --p) {
        hist[tid] = 0;
        __syncthreads();
        const unsigned long long prefix  = s_prefix;
        const unsigned long long hi_mask = (p == 7) ? 0ULL : (~0ULL << ((p + 1) * 8));
        const unsigned rem = s_remaining;
        if (p == 7) {
            // top byte has ~2-4 distinct values: ballot-dedup counting,
            // avoids a 4096-update same-address LDS atomic storm.
            #pragma unroll
            for (int i = 0; i < 16; ++i) {
                unsigned bin = (unsigned)(key[i] >> 56);
                unsigned long long todo = __ballot(1);
                while (todo) {
                    int leader  = (int)__ffsll(todo) - 1;
                    unsigned lb = __shfl(bin, leader, 64);
                    unsigned long long m = __ballot(bin == lb);
                    if (lane == leader) atomicAdd(&hist[lb], (unsigned)__popcll(m));
                    todo &= ~m;
                }
            }
        } else {
            #pragma unroll
            for (int i = 0; i < 16; ++i) {
                if (((key[i] ^ prefix) & hi_mask) == 0ULL)
                    atomicAdd(&hist[(unsigned)((key[i] >> (p * 8)) & 255ULL)], 1u);
            }
        }
        __syncthreads();
        // suffix-sum across bins: thread tid owns bin (255 - tid)
        unsigned vv = hist[255 - tid];
        unsigned inc = vv;
        #pragma unroll
        for (int off = 1; off < 64; off <<= 1) {
            unsigned n = __shfl_up(inc, off, 64);
            if ((tid & 63) >= off) inc += n;
        }
        if ((tid & 63) == 63) wtot[tid >> 6] = inc;
        __syncthreads();
        unsigned base = 0;
        for (int w = 0; w < (tid >> 6); ++w) base += wtot[w];
        inc += base;
        const unsigned cum_above = inc - vv;
        if (cum_above < rem && inc >= rem) {   // exactly one thread matches
            const unsigned new_rem = rem - cum_above;
            s_prefix    = prefix | ((unsigned long long)(255 - tid) << (p * 8));
            s_remaining = new_rem;
            if (vv == new_rem) s_done = 1;     // all prefix-equal elems selected
        }
        __syncthreads();
        if (s_done) break;
    }

    const unsigned long long K = s_prefix;
    const int done         = s_done;        // block-uniform
    const unsigned need_eq = s_remaining;

    unsigned selmask = 0, selc = 0;
    if (done) {
        #pragma unroll
        for (int i = 0; i < 16; ++i)
            if (key[i] >= K) { selmask |= (1u << i); ++selc; }
    } else {
        // full 64-bit resolution: tie-break exact duplicates by ascending index
        unsigned eqc = 0;
        #pragma unroll
        for (int i = 0; i < 16; ++i) eqc += (key[i] == K) ? 1u : 0u;
        unsigned r = block_excl_scan_256(eqc, wtot, tid);
        #pragma unroll
        for (int i = 0; i < 16; ++i) {
            bool eq  = (key[i] == K);
            bool sel = (key[i] > K) || (eq && r < need_eq);
            r += eq ? 1u : 0u;
            if (sel) { selmask |= (1u << i); ++selc; }
        }
    }
    unsigned pos = block_excl_scan_256(selc, wtot, tid);

    #pragma unroll
    for (int i = 0; i < 16; ++i) {
        if (selmask & (1u << i)) {
            if (pos < K_SEL) {   // defensive
                out_sel [(size_t)b * K_SEL + pos] = (float)(t0 + i);
                out_gate[(size_t)b * K_SEL + pos] =
                    0.1f / (1.0f + __expf(-(float)v[i]));
            }
            ++pos;
        }
    }

    // ---- losses (fp32 elementwise, fp64 accumulate) ----
    float mx = -3.0e38f;
    #pragma unroll
    for (int i = 0; i < 16; ++i) mx = fmaxf(mx, (float)v[i]);
    #pragma unroll
    for (int off = 32; off; off >>= 1) mx = fmaxf(mx, __shfl_down(mx, off, 64));
    __syncthreads();
    if ((tid & 63) == 0) dtot[tid >> 6] = (double)mx;
    __syncthreads();
    if (tid == 0) s_max = fmax(fmax(dtot[0], dtot[1]), fmax(dtot[2], dtot[3]));
    __syncthreads();
    const float m = (float)s_max;

    double bce = 0.0, se = 0.0;
    #pragma unroll
    for (int i = 0; i < 16; ++i) {
        const float l   = (float)v[i];
        const float tgt = ((selmask >> i) & 1u) ? 1.0f : 0.0f;
        bce += (double)(fmaxf(l, 0.0f) - l * tgt + log1pf(__expf(-fabsf(l))));
        se  += (double)__expf(l - m);
    }
    #pragma unroll
    for (int off = 32; off; off >>= 1) bce += __shfl_down(bce, off, 64);
    __syncthreads();
    if ((tid & 63) == 0) dtot[tid >> 6] = bce;
    __syncthreads();
    if (tid == 0) {
        double t = dtot[0] + dtot[1] + dtot[2] + dtot[3];
        __hip_atomic_store(&g_partials[b], t, __ATOMIC_RELAXED, __HIP_MEMORY_SCOPE_AGENT);
    }
    __syncthreads();
    #pragma unroll
    for (int off = 32; off; off >>= 1) se += __shfl_down(se, off, 64);
    if ((tid & 63) == 0) dtot[tid >> 6] = se;
    __syncthreads();

    if (tid == 0) {
        double z = (double)m + log(dtot[0] + dtot[1] + dtot[2] + dtot[3]);
        __hip_atomic_store(&g_partials[4 + b], z, __ATOMIC_RELAXED, __HIP_MEMORY_SCOPE_AGENT);
        __threadfence();
        unsigned old = atomicAdd(&g_done_ctr, 1u);
        s_last = (old == 3u) ? 1 : 0;
    }
    __syncthreads();

    // fused finalize: the last block to arrive computes the scalar losses
    if (s_last && tid == 0) {
        __threadfence();
        double bs = 0.0, zz = 0.0;
        for (int r2 = 0; r2 < B_DIM; ++r2) {
            bs += __hip_atomic_load(&g_partials[r2], __ATOMIC_RELAXED, __HIP_MEMORY_SCOPE_AGENT);
            double z = __hip_atomic_load(&g_partials[4 + r2], __ATOMIC_RELAXED, __HIP_MEMORY_SCOPE_AGENT);
            zz += z * z;
        }
        out_loss[0] = (float)(0.001 * bs / (double)(B_DIM * T_DIM));
        out_loss[1] = (float)(0.001 * zz / (double)B_DIM);
    }
}

// ---------------------------------------------------------------------------
extern "C" void kernel_launch(void* const* d_in, const int* in_sizes, int n_in,
                              void* d_out, int out_size, void* d_ws, size_t ws_size,
                              hipStream_t stream) {
    const float* x = (const float*)d_in[0];   // (4, 4096, 2048) fp32
    const float* W = (const float*)d_in[1];   // (1, 2048) fp32
    float* out = (float*)d_out;               // fp32 outputs

    // out layout (float elems): sel[8192] | gate[8192] | raw[16384] | aux | z
    router_matvec <<<(B_DIM * T_DIM) / 4, 256, 0, stream>>>(x, W, out + 16384);
    router_select <<<B_DIM, 256, 0, stream>>>(out, out + 8192, out + 32768);
}

// Round 5
// 36.768 us; speedup vs baseline: 1.7265x; 1.2362x over previous
//
#include <hip/hip_runtime.h>

#define B_DIM 4
#define T_DIM 4096
#define D_DIM 2048
#define K_SEL 2048   // top_k = int(0.5 * 4096)
#define NB    2048   // linear buckets
#define CAP   1024   // boundary-candidate capacity (typical count ~6)

// Module-scope scratch (deterministic: fully rewritten every launch).
__device__ __align__(16) double g_logits[B_DIM * T_DIM];
__device__ double g_partials[2 * B_DIM];
__device__ unsigned g_done_ctr;   // reset by K1 each launch

typedef float f4v __attribute__((ext_vector_type(4)));

// order-preserving map: double -> uint64 (larger key <=> larger double)
__device__ inline unsigned long long keymap(double d) {
    unsigned long long b = (unsigned long long)__double_as_longlong(d);
    return (b & 0x8000000000000000ULL) ? ~b : (b | 0x8000000000000000ULL);
}

// exclusive scan of one unsigned per thread across 256 threads (4 waves)
__device__ inline unsigned block_excl_scan_256(unsigned v, unsigned* wtot, int tid) {
    unsigned inc = v;
    #pragma unroll
    for (int off = 1; off < 64; off <<= 1) {
        unsigned n = __shfl_up(inc, off, 64);
        if ((tid & 63) >= off) inc += n;
    }
    __syncthreads();                       // protect wtot from previous use
    if ((tid & 63) == 63) wtot[tid >> 6] = inc;
    __syncthreads();
    unsigned base = 0;
    for (int w = 0; w < (tid >> 6); ++w) base += wtot[w];
    return base + inc - v;
}

// ---------------------------------------------------------------------------
// K1: logits[b,t] = dot(x[b,t,:], W) in fp64.  One wave per row.
__global__ __launch_bounds__(256) void router_matvec(
    const float* __restrict__ x, const float* __restrict__ W,
    float* __restrict__ raw_out)
{
    if (blockIdx.x == 0 && threadIdx.x == 0) g_done_ctr = 0;  // reset fuse ctr
    const int row  = blockIdx.x * 4 + (threadIdx.x >> 6);   // 16384 rows
    const int lane = threadIdx.x & 63;
    const f4v* xr = (const f4v*)(x + (size_t)row * D_DIM);
    const f4v* wr = (const f4v*)W;
    double a0 = 0.0, a1 = 0.0;
    #pragma unroll
    for (int j = 0; j < 8; ++j) {
        f4v a = __builtin_nontemporal_load(xr + lane + j * 64);  // streamed
        f4v w = wr[lane + j * 64];                               // cached (8 KB)
        a0 = fma((double)a.x, (double)w.x, a0);
        a0 = fma((double)a.y, (double)w.y, a0);
        a1 = fma((double)a.z, (double)w.z, a1);
        a1 = fma((double)a.w, (double)w.w, a1);
    }
    double acc = a0 + a1;
    #pragma unroll
    for (int off = 32; off; off >>= 1) acc += __shfl_down(acc, off, 64);
    if (lane == 0) {
        g_logits[row] = acc;
        raw_out[row]  = (float)acc;
    }
}

// ---------------------------------------------------------------------------
// K2: per batch row — single-pass linear-bucket select, exact 64-bit
// threshold fix-up, compaction, losses, fused finalize (last block).
__global__ __launch_bounds__(256) void router_select(
    float* __restrict__ out_sel,
    float* __restrict__ out_gate,
    float* __restrict__ out_loss)
{
    const int b   = blockIdx.x;
    const int tid = threadIdx.x;

    __shared__ unsigned hist[NB];              // 8 KiB
    __shared__ unsigned long long ckey[CAP];   // 8 KiB
    __shared__ unsigned wtot[4];
    __shared__ double dtot[8];
    __shared__ double s_lo, s_hi;
    __shared__ int s_qb;
    __shared__ unsigned s_rem, s_ccnt, s_needeq;
    __shared__ unsigned long long s_K;
    __shared__ int s_multi;

    // ---- per-thread strip of 16 consecutive tokens, loaded straight from
    // global (avoids the 32-way LDS bank conflict of a [4096] double array
    // read at 128 B/lane stride; L1 absorbs the 16B-of-128B line touches) ----
    const int t0 = tid * 16;
    const double2* gp = (const double2*)(g_logits + (size_t)b * T_DIM + t0);
    double v[16];
    #pragma unroll
    for (int i = 0; i < 8; ++i) { double2 d = gp[i]; v[2*i] = d.x; v[2*i+1] = d.y; }
    unsigned long long key[16];
    #pragma unroll
    for (int i = 0; i < 16; ++i) key[i] = keymap(v[i]);

    // ---- row min/max (max reused for logsumexp) ----
    double mn = v[0], mx = v[0];
    #pragma unroll
    for (int i = 1; i < 16; ++i) { mn = fmin(mn, v[i]); mx = fmax(mx, v[i]); }
    #pragma unroll
    for (int off = 32; off; off >>= 1) {
        mn = fmin(mn, __shfl_down(mn, off, 64));
        mx = fmax(mx, __shfl_down(mx, off, 64));
    }
    if ((tid & 63) == 0) { dtot[tid >> 6] = mn; dtot[4 + (tid >> 6)] = mx; }
    // zero histogram while the reduce settles
    #pragma unroll
    for (int h = 0; h < NB / 256; ++h) hist[tid + h * 256] = 0;
    __syncthreads();
    if (tid == 0) {
        s_lo = fmin(fmin(dtot[0], dtot[1]), fmin(dtot[2], dtot[3]));
        s_hi = fmax(fmax(dtot[4], dtot[5]), fmax(dtot[6], dtot[7]));
        s_ccnt = 0;
    }
    __syncthreads();

    const double lo   = s_lo;
    const double span = s_hi - lo;
    const double scale = (span > 0.0) ? (double)NB / span : 0.0;
    auto bkt = [&](double x) -> int {
        int q = (int)((x - lo) * scale);
        return q > (NB - 1) ? (NB - 1) : q;
    };

    // ---- single histogram pass (low contention: ~2 elems/bucket) ----
    #pragma unroll
    for (int i = 0; i < 16; ++i) atomicAdd(&hist[bkt(v[i])], 1u);
    __syncthreads();

    // ---- suffix scan over buckets, descending: thread tid owns [B0,B0+8) ----
    const int B0 = (255 - tid) * 8;
    unsigned hc[8]; unsigned tsum = 0;
    #pragma unroll
    for (int j = 0; j < 8; ++j) { hc[j] = hist[B0 + j]; tsum += hc[j]; }
    unsigned above = block_excl_scan_256(tsum, wtot, tid);  // counts in higher buckets
    {
        unsigned run = above;
        for (int j = 7; j >= 0; --j) {
            unsigned cnt = hc[j];
            if (run < K_SEL && run + cnt >= K_SEL) { s_qb = B0 + j; s_rem = K_SEL - run; }
            run += cnt;
        }
    }
    __syncthreads();

    const int qb = s_qb;
    const unsigned rem = s_rem;   // how many to take from boundary bucket

    // ---- gather boundary-bucket candidates ----
    #pragma unroll
    for (int i = 0; i < 16; ++i) {
        if (bkt(v[i]) == qb) {
            unsigned slot = atomicAdd(&s_ccnt, 1u);
            if (slot < CAP) ckey[slot] = key[i];
        }
    }
    __syncthreads();
    const unsigned c = (s_ccnt < CAP) ? s_ccnt : CAP;

    // ---- rem-th largest among candidates (exact 64-bit, dup-aware) ----
    if (tid < (int)c) {
        unsigned long long kj = ckey[tid];
        unsigned g = 0, e = 0;
        for (unsigned u = 0; u < c; ++u) {
            unsigned long long ku = ckey[u];
            g += (ku > kj) ? 1u : 0u;
            e += (ku == kj) ? 1u : 0u;
        }
        if (g < rem && g + e >= rem) { s_K = kj; s_needeq = rem - g; s_multi = (e > 1); }
    }
    __syncthreads();

    const unsigned long long K = s_K;
    const unsigned needeq = s_needeq;
    const int multi = s_multi;     // block-uniform

    // eq-rank scan only when the threshold key is duplicated (rare)
    unsigned eqrank = 0;
    if (multi) {
        unsigned eqc = 0;
        #pragma unroll
        for (int i = 0; i < 16; ++i) eqc += (key[i] == K) ? 1u : 0u;
        eqrank = block_excl_scan_256(eqc, wtot, tid);
    }

    unsigned selmask = 0, selc = 0;
    {
        unsigned r = eqrank;
        #pragma unroll
        for (int i = 0; i < 16; ++i) {
            const int bq  = bkt(v[i]);
            const bool eq = (key[i] == K);
            const bool sel = (bq > qb) ||
                             (bq == qb && (key[i] > K || (eq && r < needeq)));
            if (eq) ++r;
            if (sel) { selmask |= (1u << i); ++selc; }
        }
    }
    unsigned pos = block_excl_scan_256(selc, wtot, tid);

    #pragma unroll
    for (int i = 0; i < 16; ++i) {
        if (selmask & (1u << i)) {
            if (pos < K_SEL) {   // defensive
                out_sel [(size_t)b * K_SEL + pos] = (float)(t0 + i);
                out_gate[(size_t)b * K_SEL + pos] =
                    0.1f / (1.0f + __expf(-(float)v[i]));
            }
            ++pos;
        }
    }

    // ---- losses (fp32 elementwise, fp64 accumulate); m = row max ----
    const float m = (float)s_hi;
    double bce = 0.0, se = 0.0;
    #pragma unroll
    for (int i = 0; i < 16; ++i) {
        const float l   = (float)v[i];
        const float tgt = ((selmask >> i) & 1u) ? 1.0f : 0.0f;
        bce += (double)(fmaxf(l, 0.0f) - l * tgt + log1pf(__expf(-fabsf(l))));
        se  += (double)__expf(l - m);
    }
    #pragma unroll
    for (int off = 32; off; off >>= 1) {
        bce += __shfl_down(bce, off, 64);
        se  += __shfl_down(se,  off, 64);
    }
    __syncthreads();               // protect dtot reuse
    if ((tid & 63) == 0) { dtot[tid >> 6] = bce; dtot[4 + (tid >> 6)] = se; }
    __syncthreads();

    if (tid == 0) {
        double bsum = dtot[0] + dtot[1] + dtot[2] + dtot[3];
        double z = (double)m + log(dtot[4] + dtot[5] + dtot[6] + dtot[7]);
        __hip_atomic_store(&g_partials[b], bsum, __ATOMIC_RELAXED, __HIP_MEMORY_SCOPE_AGENT);
        __hip_atomic_store(&g_partials[4 + b], z, __ATOMIC_RELAXED, __HIP_MEMORY_SCOPE_AGENT);
        __threadfence();
        unsigned old = atomicAdd(&g_done_ctr, 1u);
        if (old == 3u) {           // fused finalize: last block computes losses
            __threadfence();
            double bs = 0.0, zz = 0.0;
            for (int r2 = 0; r2 < B_DIM; ++r2) {
                bs += __hip_atomic_load(&g_partials[r2], __ATOMIC_RELAXED, __HIP_MEMORY_SCOPE_AGENT);
                double zv = __hip_atomic_load(&g_partials[4 + r2], __ATOMIC_RELAXED, __HIP_MEMORY_SCOPE_AGENT);
                zz += zv * zv;
            }
            out_loss[0] = (float)(0.001 * bs / (double)(B_DIM * T_DIM));
            out_loss[1] = (float)(0.001 * zz / (double)B_DIM);
        }
    }
}

// ---------------------------------------------------------------------------
extern "C" void kernel_launch(void* const* d_in, const int* in_sizes, int n_in,
                              void* d_out, int out_size, void* d_ws, size_t ws_size,
                              hipStream_t stream) {
    const float* x = (const float*)d_in[0];   // (4, 4096, 2048) fp32
    const float* W = (const float*)d_in[1];   // (1, 2048) fp32
    float* out = (float*)d_out;               // fp32 outputs

    // out layout (float elems): sel[8192] | gate[8192] | raw[16384] | aux | z
    router_matvec <<<(B_DIM * T_DIM) / 4, 256, 0, stream>>>(x, W, out + 16384);
    router_select <<<B_DIM, 256, 0, stream>>>(out, out + 8192, out + 32768);
}

// Round 6
// 34.839 us; speedup vs baseline: 1.8221x; 1.0554x over previous
//
#include <hip/hip_runtime.h>

#define B_DIM 4
#define T_DIM 4096
#define D_DIM 2048
#define K_SEL 2048   // top_k = int(0.5 * 4096)
#define NB    2048   // linear buckets
#define CAP   1024   // boundary-candidate capacity (typical count ~6)

// Module-scope scratch (deterministic: fully rewritten every launch).
__device__ __align__(16) double g_logits[B_DIM * T_DIM];
__device__ double g_partials[2 * B_DIM];
__device__ unsigned g_done_ctr;   // reset by K1 each launch

typedef float f4v __attribute__((ext_vector_type(4)));

// order-preserving map: double -> uint64 (larger key <=> larger double)
__device__ inline unsigned long long keymap(double d) {
    unsigned long long b = (unsigned long long)__double_as_longlong(d);
    return (b & 0x8000000000000000ULL) ? ~b : (b | 0x8000000000000000ULL);
}

// exclusive scan of one unsigned per thread across 1024 threads (16 waves)
__device__ inline unsigned block_excl_scan_1024(unsigned v, unsigned* wtot, int tid) {
    unsigned inc = v;
    #pragma unroll
    for (int off = 1; off < 64; off <<= 1) {
        unsigned n = __shfl_up(inc, off, 64);
        if ((tid & 63) >= off) inc += n;
    }
    __syncthreads();                       // protect wtot from previous use
    if ((tid & 63) == 63) wtot[tid >> 6] = inc;
    __syncthreads();
    unsigned base = 0;
    for (int w = 0; w < (tid >> 6); ++w) base += wtot[w];
    return base + inc - v;
}

// ---------------------------------------------------------------------------
// K1: logits[b,t] = dot(x[b,t,:], W) in fp64.  One wave per row.
__global__ __launch_bounds__(256) void router_matvec(
    const float* __restrict__ x, const float* __restrict__ W,
    float* __restrict__ raw_out)
{
    if (blockIdx.x == 0 && threadIdx.x == 0) g_done_ctr = 0;  // reset fuse ctr
    const int row  = blockIdx.x * 4 + (threadIdx.x >> 6);   // 16384 rows
    const int lane = threadIdx.x & 63;
    const f4v* xr = (const f4v*)(x + (size_t)row * D_DIM);
    const f4v* wr = (const f4v*)W;
    double a0 = 0.0, a1 = 0.0;
    #pragma unroll
    for (int j = 0; j < 8; ++j) {
        f4v a = __builtin_nontemporal_load(xr + lane + j * 64);  // streamed
        f4v w = wr[lane + j * 64];                               // cached (8 KB)
        a0 = fma((double)a.x, (double)w.x, a0);
        a0 = fma((double)a.y, (double)w.y, a0);
        a1 = fma((double)a.z, (double)w.z, a1);
        a1 = fma((double)a.w, (double)w.w, a1);
    }
    double acc = a0 + a1;
    #pragma unroll
    for (int off = 32; off; off >>= 1) acc += __shfl_down(acc, off, 64);
    if (lane == 0) {
        g_logits[row] = acc;
        raw_out[row]  = (float)acc;
    }
}

// ---------------------------------------------------------------------------
// K2: per batch row (1024 threads) — single-pass linear-bucket select, exact
// 64-bit threshold fix-up, compaction, losses, fused finalize (last block).
__global__ __launch_bounds__(1024) void router_select(
    float* __restrict__ out_sel,
    float* __restrict__ out_gate,
    float* __restrict__ out_loss)
{
    const int b   = blockIdx.x;
    const int tid = threadIdx.x;

    __shared__ unsigned hist[NB];              // 8 KiB
    __shared__ unsigned long long ckey[CAP];   // 8 KiB
    __shared__ unsigned wtot[16];
    __shared__ double dtot[32];
    __shared__ double s_lo, s_hi;
    __shared__ int s_qb;
    __shared__ unsigned s_rem, s_ccnt, s_needeq;
    __shared__ unsigned long long s_K;
    __shared__ int s_multi;

    // ---- per-thread strip of 4 consecutive tokens, straight from global
    // (32 B/lane contiguous -> fully coalesced 2 KB per wave) ----
    const int t0 = tid * 4;
    const double2* gp = (const double2*)(g_logits + (size_t)b * T_DIM + t0);
    double v[4];
    { double2 d0 = gp[0], d1 = gp[1]; v[0]=d0.x; v[1]=d0.y; v[2]=d1.x; v[3]=d1.y; }
    unsigned long long key[4];
    #pragma unroll
    for (int i = 0; i < 4; ++i) key[i] = keymap(v[i]);

    // ---- row min/max (max reused for logsumexp) ----
    double mn = v[0], mx = v[0];
    #pragma unroll
    for (int i = 1; i < 4; ++i) { mn = fmin(mn, v[i]); mx = fmax(mx, v[i]); }
    #pragma unroll
    for (int off = 32; off; off >>= 1) {
        mn = fmin(mn, __shfl_down(mn, off, 64));
        mx = fmax(mx, __shfl_down(mx, off, 64));
    }
    if ((tid & 63) == 0) { dtot[tid >> 6] = mn; dtot[16 + (tid >> 6)] = mx; }
    // zero histogram while the reduce settles
    hist[tid] = 0; hist[tid + 1024] = 0;
    __syncthreads();
    if (tid == 0) {
        double l0 = dtot[0], h0 = dtot[16];
        for (int w = 1; w < 16; ++w) {
            l0 = fmin(l0, dtot[w]); h0 = fmax(h0, dtot[16 + w]);
        }
        s_lo = l0; s_hi = h0; s_ccnt = 0;
    }
    __syncthreads();

    const double lo   = s_lo;
    const double span = s_hi - lo;
    const double scale = (span > 0.0) ? (double)NB / span : 0.0;
    auto bkt = [&](double x) -> int {
        int q = (int)((x - lo) * scale);
        return q > (NB - 1) ? (NB - 1) : q;
    };

    // ---- single histogram pass (low contention: ~2 elems/bucket) ----
    #pragma unroll
    for (int i = 0; i < 4; ++i) atomicAdd(&hist[bkt(v[i])], 1u);
    __syncthreads();

    // ---- suffix scan over buckets, descending: thread tid owns [B0,B0+2) ----
    const int B0 = (1023 - tid) * 2;
    unsigned hc0 = hist[B0], hc1 = hist[B0 + 1];
    unsigned above = block_excl_scan_1024(hc0 + hc1, wtot, tid);
    {
        unsigned run = above;            // counts in buckets above B0+1
        if (run < K_SEL && run + hc1 >= K_SEL) { s_qb = B0 + 1; s_rem = K_SEL - run; }
        run += hc1;
        if (run < K_SEL && run + hc0 >= K_SEL) { s_qb = B0;     s_rem = K_SEL - run; }
    }
    __syncthreads();

    const int qb = s_qb;
    const unsigned rem = s_rem;   // how many to take from boundary bucket

    // ---- gather boundary-bucket candidates ----
    #pragma unroll
    for (int i = 0; i < 4; ++i) {
        if (bkt(v[i]) == qb) {
            unsigned slot = atomicAdd(&s_ccnt, 1u);
            if (slot < CAP) ckey[slot] = key[i];
        }
    }
    __syncthreads();
    const unsigned c = (s_ccnt < CAP) ? s_ccnt : CAP;

    // ---- rem-th largest among candidates (exact 64-bit, dup-aware) ----
    if (tid < (int)c) {
        unsigned long long kj = ckey[tid];
        unsigned g = 0, e = 0;
        for (unsigned u = 0; u < c; ++u) {
            unsigned long long ku = ckey[u];
            g += (ku > kj) ? 1u : 0u;
            e += (ku == kj) ? 1u : 0u;
        }
        if (g < rem && g + e >= rem) { s_K = kj; s_needeq = rem - g; s_multi = (e > 1); }
    }
    __syncthreads();

    const unsigned long long K = s_K;
    const unsigned needeq = s_needeq;
    const int multi = s_multi;     // block-uniform

    // eq-rank scan only when the threshold key is duplicated (rare)
    unsigned eqrank = 0;
    if (multi) {
        unsigned eqc = 0;
        #pragma unroll
        for (int i = 0; i < 4; ++i) eqc += (key[i] == K) ? 1u : 0u;
        eqrank = block_excl_scan_1024(eqc, wtot, tid);
    }

    unsigned selmask = 0, selc = 0;
    {
        unsigned r = eqrank;
        #pragma unroll
        for (int i = 0; i < 4; ++i) {
            const int bq  = bkt(v[i]);
            const bool eq = (key[i] == K);
            const bool sel = (bq > qb) ||
                             (bq == qb && (key[i] > K || (eq && r < needeq)));
            if (eq) ++r;
            if (sel) { selmask |= (1u << i); ++selc; }
        }
    }
    unsigned pos = block_excl_scan_1024(selc, wtot, tid);

    #pragma unroll
    for (int i = 0; i < 4; ++i) {
        if (selmask & (1u << i)) {
            if (pos < K_SEL) {   // defensive
                out_sel [(size_t)b * K_SEL + pos] = (float)(t0 + i);
                out_gate[(size_t)b * K_SEL + pos] =
                    0.1f / (1.0f + __expf(-(float)v[i]));
            }
            ++pos;
        }
    }

    // ---- losses (fp32 elementwise, fp64 accumulate); m = row max ----
    const float m = (float)s_hi;
    double bce = 0.0, se = 0.0;
    #pragma unroll
    for (int i = 0; i < 4; ++i) {
        const float l   = (float)v[i];
        const float tgt = ((selmask >> i) & 1u) ? 1.0f : 0.0f;
        bce += (double)(fmaxf(l, 0.0f) - l * tgt + log1pf(__expf(-fabsf(l))));
        se  += (double)__expf(l - m);
    }
    #pragma unroll
    for (int off = 32; off; off >>= 1) {
        bce += __shfl_down(bce, off, 64);
        se  += __shfl_down(se,  off, 64);
    }
    __syncthreads();               // protect dtot reuse
    if ((tid & 63) == 0) { dtot[tid >> 6] = bce; dtot[16 + (tid >> 6)] = se; }
    __syncthreads();

    if (tid == 0) {
        double bsum = 0.0, sesum = 0.0;
        for (int w = 0; w < 16; ++w) { bsum += dtot[w]; sesum += dtot[16 + w]; }
        double z = (double)m + log(sesum);
        __hip_atomic_store(&g_partials[b], bsum, __ATOMIC_RELAXED, __HIP_MEMORY_SCOPE_AGENT);
        __hip_atomic_store(&g_partials[4 + b], z, __ATOMIC_RELAXED, __HIP_MEMORY_SCOPE_AGENT);
        __threadfence();
        unsigned old = atomicAdd(&g_done_ctr, 1u);
        if (old == 3u) {           // fused finalize: last block computes losses
            __threadfence();
            double bs = 0.0, zz = 0.0;
            for (int r2 = 0; r2 < B_DIM; ++r2) {
                bs += __hip_atomic_load(&g_partials[r2], __ATOMIC_RELAXED, __HIP_MEMORY_SCOPE_AGENT);
                double zv = __hip_atomic_load(&g_partials[4 + r2], __ATOMIC_RELAXED, __HIP_MEMORY_SCOPE_AGENT);
                zz += zv * zv;
            }
            out_loss[0] = (float)(0.001 * bs / (double)(B_DIM * T_DIM));
            out_loss[1] = (float)(0.001 * zz / (double)B_DIM);
        }
    }
}

// ---------------------------------------------------------------------------
extern "C" void kernel_launch(void* const* d_in, const int* in_sizes, int n_in,
                              void* d_out, int out_size, void* d_ws, size_t ws_size,
                              hipStream_t stream) {
    const float* x = (const float*)d_in[0];   // (4, 4096, 2048) fp32
    const float* W = (const float*)d_in[1];   // (1, 2048) fp32
    float* out = (float*)d_out;               // fp32 outputs

    // out layout (float elems): sel[8192] | gate[8192] | raw[16384] | aux | z
    router_matvec <<<(B_DIM * T_DIM) / 4, 256, 0, stream>>>(x, W, out + 16384);
    router_select <<<B_DIM, 1024, 0, stream>>>(out, out + 8192, out + 32768);
}